// Round 6
// baseline (627.815 us; speedup 1.0000x reference)
//
#include <hip/hip_runtime.h>
#include <math.h>

typedef __attribute__((ext_vector_type(8))) short short8;
typedef __attribute__((ext_vector_type(4))) float f32x4;
typedef unsigned short u16;
typedef unsigned int u32;

// ssp(x) = softplus(x) - log(2), fast form
__device__ __forceinline__ float ssp(float x) {
    float ax = fabsf(x);
    return fmaxf(x, 0.0f) + __logf(1.0f + __expf(-ax)) - 0.69314718055994530942f;
}

// fp32 -> bf16 round-to-nearest-even
__device__ __forceinline__ u16 f2bf(float x) {
    u32 u = __float_as_uint(x);
    u32 r = (u + 0x7FFFu + ((u >> 16) & 1u)) >> 16;
    return (u16)r;
}

// ---------------------------------------------------------------------------
// Merged CSR build for BOTH edge sets: counts[2N] (main | hull)
// ---------------------------------------------------------------------------
__global__ __launch_bounds__(256) void hist2_kernel(
    const int* __restrict__ tgt_m, int E,
    const int* __restrict__ tgt_h, int Eh,
    int* __restrict__ counts, int N)
{
    int i = blockIdx.x * 256 + threadIdx.x;
    if (i < E) atomicAdd(&counts[tgt_m[i]], 1);
    else if (i < E + Eh) atomicAdd(&counts[N + tgt_h[i - E]], 1);
}

__global__ __launch_bounds__(1024) void scan1_kernel(
    const int* __restrict__ counts, int* __restrict__ offsets,
    int* __restrict__ bsums, int n)
{
    __shared__ int buf[2][1024];
    const int tid = threadIdx.x;
    const int idx = blockIdx.x * 1024 + tid;
    int val = (idx < n) ? counts[idx] : 0;
    int cur = 0;
    buf[0][tid] = val;
    __syncthreads();
    for (int off = 1; off < 1024; off <<= 1) {
        int x = buf[cur][tid];
        if (tid >= off) x += buf[cur][tid - off];
        buf[cur ^ 1][tid] = x;
        cur ^= 1;
        __syncthreads();
    }
    if (idx < n) offsets[idx] = buf[cur][tid] - val;   // block-local exclusive
    if (tid == 1023) bsums[blockIdx.x] = buf[cur][tid];
}

// nb <= 256 (2N=200000 -> nb=196)
__global__ __launch_bounds__(256) void scan2_kernel(
    int* __restrict__ bsums, int nb, int* __restrict__ offsets, int n)
{
    __shared__ int b[2][256];
    const int tid = threadIdx.x;
    int val = (tid < nb) ? bsums[tid] : 0;
    int cur = 0;
    b[0][tid] = val;
    __syncthreads();
    for (int off = 1; off < 256; off <<= 1) {
        int x = b[cur][tid];
        if (tid >= off) x += b[cur][tid - off];
        b[cur ^ 1][tid] = x;
        cur ^= 1;
        __syncthreads();
    }
    if (tid < nb) bsums[tid] = b[cur][tid] - val;      // exclusive
    if (tid == 255) offsets[n] = b[cur][255];          // grand total
}

__global__ __launch_bounds__(256) void scan3_kernel(
    int* __restrict__ offsets, const int* __restrict__ bsums, int n)
{
    int idx = blockIdx.x * 256 + threadIdx.x;
    if (idx < n) offsets[idx] += bsums[idx >> 10];
}

__global__ __launch_bounds__(256) void place2_kernel(
    const int* __restrict__ tgt_m, int E,
    const int* __restrict__ tgt_h, int Eh,
    const int* __restrict__ offsets, int* __restrict__ cursors,
    int* __restrict__ perm, int N)
{
    int i = blockIdx.x * 256 + threadIdx.x;
    if (i < E) {
        int slot = tgt_m[i];
        int pos = offsets[slot] + atomicAdd(&cursors[slot], 1);
        perm[pos] = i;                      // main edge id
    } else if (i < E + Eh) {
        int slot = N + tgt_h[i - E];
        int pos = offsets[slot] + atomicAdd(&cursors[slot], 1);
        perm[pos] = i - E;                  // hull-local edge id
    }
}

// ---------------------------------------------------------------------------
// Convert 5 weight matrices fp32 -> bf16 into ws: W1|W1h|W2|W2h|Wc  (98304)
// ---------------------------------------------------------------------------
__global__ __launch_bounds__(256) void wconvert_kernel(
    const float* __restrict__ W1, const float* __restrict__ W1h,
    const float* __restrict__ W2, const float* __restrict__ W2h,
    const float* __restrict__ Wc, u16* __restrict__ dst)
{
    int i = blockIdx.x * 256 + threadIdx.x;
    if (i >= 98304) return;
    const float* src; int off;
    if      (i < 16384) { src = W1;  off = i; }
    else if (i < 32768) { src = W1h; off = i - 16384; }
    else if (i < 49152) { src = W2;  off = i - 32768; }
    else if (i < 65536) { src = W2h; off = i - 49152; }
    else                { src = Wc;  off = i - 65536; }
    dst[i] = f2bf(src[off]);
}

// ---------------------------------------------------------------------------
// Fused gather + 3-layer MFMA MLP. Block = 64 nodes x 4 waves, NO barriers:
// each wave owns rows [w*16, w*16+16) of every LDS tile — gather, all MFMA
// layers, and the epilogue stay within the wave's own stripe, so waves drift
// freely and gather (HBM-bound) overlaps MFMA/ssp (compute-bound).
// LDS tiles [64][128] bf16 XOR chunk-swizzled: chunk' = c ^ (row&7).
// Tile aliasing (3 tiles, 48KB -> 3 blocks/CU):
//   stage: accm->X0, acch->X1
//   L1m: X0->X2   L1h: X1->X0   L2m: X2->X1(zm)   L2h: X0->X2(zh)
//   final: X1,X2 -> out
// ---------------------------------------------------------------------------
#define MT 64

#define CHUNK_IDX(row, ch) (((row) * 16 + ((ch) ^ ((row) & 7))))
#define AFRAG(ls, row, ch) (*(const short8*)&(ls)[CHUNK_IDX(row, ch) * 8])

__device__ __forceinline__ f32x4 gather_rows(
    const f32x4* __restrict__ src, const int* __restrict__ perm,
    int k, int kend, int c4)
{
    f32x4 s = {0.f, 0.f, 0.f, 0.f};
    for (; k + 4 <= kend; k += 4) {
        int p0 = perm[k], p1 = perm[k + 1], p2 = perm[k + 2], p3 = perm[k + 3];
        f32x4 a = __builtin_nontemporal_load(&src[(size_t)p0 * 32 + c4]);
        f32x4 b = __builtin_nontemporal_load(&src[(size_t)p1 * 32 + c4]);
        f32x4 c = __builtin_nontemporal_load(&src[(size_t)p2 * 32 + c4]);
        f32x4 d = __builtin_nontemporal_load(&src[(size_t)p3 * 32 + c4]);
        s += (a + b) + (c + d);
    }
    for (; k + 2 <= kend; k += 2) {
        int p0 = perm[k], p1 = perm[k + 1];
        s += __builtin_nontemporal_load(&src[(size_t)p0 * 32 + c4])
           + __builtin_nontemporal_load(&src[(size_t)p1 * 32 + c4]);
    }
    if (k < kend)
        s += __builtin_nontemporal_load(&src[(size_t)perm[k] * 32 + c4]);
    return s;
}

__device__ __forceinline__ void layer128(
    const u16* __restrict__ ls, const u16* __restrict__ W,
    const float* __restrict__ bias, u16* __restrict__ dst,
    int rw, int lr, int kc, bool act)
{
    const int arow = rw + lr;
    short8 af[4];
    #pragma unroll
    for (int s = 0; s < 4; s++) af[s] = AFRAG(ls, arow, s * 4 + kc);
    #pragma unroll
    for (int nt = 0; nt < 8; nt++) {
        const int bcol = nt * 16 + lr;
        const short8* wr = (const short8*)(W + bcol * 128);
        f32x4 acc = {0.f, 0.f, 0.f, 0.f};
        #pragma unroll
        for (int s = 0; s < 4; s++)
            acc = __builtin_amdgcn_mfma_f32_16x16x32_bf16(af[s], wr[s * 4 + kc], acc, 0, 0, 0);
        const float bn = bias[bcol];
        #pragma unroll
        for (int r = 0; r < 4; r++) {
            const int drow = rw + kc * 4 + r;
            float val = acc[r] + bn;
            if (act) val = ssp(val);
            dst[CHUNK_IDX(drow, bcol >> 3) * 8 + (bcol & 7)] = f2bf(val);
        }
    }
}

__global__ __launch_bounds__(256) void fused_mlp_kernel(
    const float* __restrict__ e, const float* __restrict__ eh,
    const int* __restrict__ perm, const int* __restrict__ offsets,
    const u16* __restrict__ Wbf,
    const float* __restrict__ b1, const float* __restrict__ b1h,
    const float* __restrict__ b2, const float* __restrict__ b2h,
    const float* __restrict__ bc,
    const float* __restrict__ v, float* __restrict__ out, int n)
{
    __shared__ __align__(16) u16 X0[MT * 128];
    __shared__ __align__(16) u16 X1[MT * 128];
    __shared__ __align__(16) u16 X2[MT * 128];

    const int tid = threadIdx.x;
    const int l   = tid & 63;
    const int w   = tid >> 6;
    const int rw  = w * 16;
    const int lr  = l & 15;
    const int kc  = l >> 4;
    const int node0 = blockIdx.x * MT;

    const u16* W1  = Wbf;
    const u16* W1h = Wbf + 16384;
    const u16* W2  = Wbf + 32768;
    const u16* W2h = Wbf + 49152;
    const u16* Wc  = Wbf + 65536;

    // ---- per-wave gather: 2 nodes at a time (one per 32-lane half) ----
    const int hw = l >> 5;
    const int c4 = l & 31;
    const int ch = c4 >> 1;
    const int hf = (c4 & 1) * 4;
    for (int j = hw; j < 16; j += 2) {
        const int row  = rw + j;
        const int node = node0 + row;
        f32x4 sm = {0.f, 0.f, 0.f, 0.f};
        f32x4 sh = {0.f, 0.f, 0.f, 0.f};
        if (node < n) {
            sm = gather_rows((const f32x4*)e,  perm, offsets[node],     offsets[node + 1],     c4);
            sh = gather_rows((const f32x4*)eh, perm, offsets[n + node], offsets[n + node + 1], c4);
        }
        ushort4 om, oh;
        om.x = f2bf(sm.x); om.y = f2bf(sm.y); om.z = f2bf(sm.z); om.w = f2bf(sm.w);
        oh.x = f2bf(sh.x); oh.y = f2bf(sh.y); oh.z = f2bf(sh.z); oh.w = f2bf(sh.w);
        *(ushort4*)&X0[CHUNK_IDX(row, ch) * 8 + hf] = om;
        *(ushort4*)&X1[CHUNK_IDX(row, ch) * 8 + hf] = oh;
    }

    // ---- 3-layer MFMA chain, wave-local (no barriers) ----
    layer128(X0, W1,  b1,  X2, rw, lr, kc, true);    // h1m
    layer128(X1, W1h, b1h, X0, rw, lr, kc, true);    // h1h
    layer128(X2, W2,  b2,  X1, rw, lr, kc, false);   // zm
    layer128(X0, W2h, b2h, X2, rw, lr, kc, false);   // zh

    // ---- final: out = v + ssp(cat(zm,zh) @ Wc^T + bc) ----
    {
        const int arow = rw + lr;
        short8 af[8];
        #pragma unroll
        for (int s = 0; s < 4; s++) af[s]     = AFRAG(X1, arow, s * 4 + kc);
        #pragma unroll
        for (int s = 0; s < 4; s++) af[s + 4] = AFRAG(X2, arow, s * 4 + kc);
        #pragma unroll
        for (int nt = 0; nt < 8; nt++) {
            const int bcol = nt * 16 + lr;
            const short8* wr = (const short8*)(Wc + bcol * 256);
            f32x4 acc = {0.f, 0.f, 0.f, 0.f};
            #pragma unroll
            for (int s = 0; s < 8; s++)
                acc = __builtin_amdgcn_mfma_f32_16x16x32_bf16(af[s], wr[s * 4 + kc], acc, 0, 0, 0);
            const float bn = bc[bcol];
            #pragma unroll
            for (int r = 0; r < 4; r++) {
                const int drow = rw + kc * 4 + r;
                const int node = node0 + drow;
                if (node < n) {
                    size_t off = (size_t)node * 128 + bcol;
                    out[off] = v[off] + ssp(acc[r] + bn);
                }
            }
        }
    }
}

extern "C" void kernel_launch(void* const* d_in, const int* in_sizes, int n_in,
                              void* d_out, int out_size, void* d_ws, size_t ws_size,
                              hipStream_t stream)
{
    const float* v    = (const float*)d_in[0];
    const float* e    = (const float*)d_in[1];
    const int*   ei   = (const int*)  d_in[2];
    const float* eh   = (const float*)d_in[3];
    const int*   eih  = (const int*)  d_in[4];
    const float* W1   = (const float*)d_in[5];
    const float* b1   = (const float*)d_in[6];
    const float* W2   = (const float*)d_in[7];
    const float* b2   = (const float*)d_in[8];
    const float* W1h  = (const float*)d_in[9];
    const float* b1h  = (const float*)d_in[10];
    const float* W2h  = (const float*)d_in[11];
    const float* b2h  = (const float*)d_in[12];
    const float* Wc   = (const float*)d_in[13];
    const float* bc   = (const float*)d_in[14];
    float* out = (float*)d_out;

    const int N  = in_sizes[0] / 128;
    const int E  = (int)(in_sizes[1] / 128);
    const int Eh = (int)(in_sizes[3] / 128);
    const int n2 = 2 * N;

    // workspace layout (all 16B-aligned)
    u16* Wbf     = (u16*)d_ws;                   // 98304 bf16
    int* counts  = (int*)(Wbf + 98304);          // 2N
    int* cursors = counts + n2;                  // 2N (contiguous with counts)
    int* offsets = cursors + n2;                 // 2N+1
    int* bsums   = offsets + (n2 + 1);           // 256
    int* perm    = bsums + 256;                  // E + Eh

    const int* tgt_m = ei  + E;   // edge_index row 1 = targets
    const int* tgt_h = eih + Eh;

    const int NB = (n2 + 1023) / 1024;
    const int ET = E + Eh;

    wconvert_kernel<<<(98304 + 255) / 256, 256, 0, stream>>>(W1, W1h, W2, W2h, Wc, Wbf);

    (void)hipMemsetAsync(counts, 0, (size_t)2 * n2 * 4, stream);   // counts + cursors
    hist2_kernel <<<(ET + 255) / 256, 256, 0, stream>>>(tgt_m, E, tgt_h, Eh, counts, N);
    scan1_kernel <<<NB, 1024, 0, stream>>>(counts, offsets, bsums, n2);
    scan2_kernel <<<1, 256, 0, stream>>>(bsums, NB, offsets, n2);
    scan3_kernel <<<(n2 + 255) / 256, 256, 0, stream>>>(offsets, bsums, n2);
    place2_kernel<<<(ET + 255) / 256, 256, 0, stream>>>(tgt_m, E, tgt_h, Eh, offsets, cursors, perm, N);

    fused_mlp_kernel<<<(N + MT - 1) / MT, 256, 0, stream>>>(
        e, eh, perm, offsets, Wbf, b1, b1h, b2, b2h, bc, v, out, N);
}

// Round 7
// 607.633 us; speedup vs baseline: 1.0332x; 1.0332x over previous
//
#include <hip/hip_runtime.h>
#include <math.h>

typedef __attribute__((ext_vector_type(8))) short short8;
typedef __attribute__((ext_vector_type(4))) float f32x4;
typedef unsigned short u16;
typedef unsigned int u32;

// ssp(x) = softplus(x) - log(2) = max(x,0) + ln2*log2(1 + 2^(-|x|*log2e)) - ln2
__device__ __forceinline__ float ssp(float x) {
    const float LOG2E = 1.44269504088896340736f;
    const float LN2   = 0.69314718055994530942f;
    float t = __builtin_amdgcn_exp2f(-fabsf(x) * LOG2E);
    return fmaxf(x, 0.0f) + LN2 * __builtin_amdgcn_logf(1.0f + t) - LN2;
}

// fp32 -> bf16 round-to-nearest-even
__device__ __forceinline__ u16 f2bf(float x) {
    u32 u = __float_as_uint(x);
    u32 r = (u + 0x7FFFu + ((u >> 16) & 1u)) >> 16;
    return (u16)r;
}

// ---------------------------------------------------------------------------
// Merged CSR build for BOTH edge sets: counts[2N] (main | hull)
// ---------------------------------------------------------------------------
__global__ __launch_bounds__(256) void hist2_kernel(
    const int* __restrict__ tgt_m, int E,
    const int* __restrict__ tgt_h, int Eh,
    int* __restrict__ counts, int N)
{
    int i = blockIdx.x * 256 + threadIdx.x;
    if (i < E) atomicAdd(&counts[tgt_m[i]], 1);
    else if (i < E + Eh) atomicAdd(&counts[N + tgt_h[i - E]], 1);
}

__global__ __launch_bounds__(1024) void scan1_kernel(
    const int* __restrict__ counts, int* __restrict__ offsets,
    int* __restrict__ bsums, int n)
{
    __shared__ int buf[2][1024];
    const int tid = threadIdx.x;
    const int idx = blockIdx.x * 1024 + tid;
    int val = (idx < n) ? counts[idx] : 0;
    int cur = 0;
    buf[0][tid] = val;
    __syncthreads();
    for (int off = 1; off < 1024; off <<= 1) {
        int x = buf[cur][tid];
        if (tid >= off) x += buf[cur][tid - off];
        buf[cur ^ 1][tid] = x;
        cur ^= 1;
        __syncthreads();
    }
    if (idx < n) offsets[idx] = buf[cur][tid] - val;   // block-local exclusive
    if (tid == 1023) bsums[blockIdx.x] = buf[cur][tid];
}

// nb <= 256 (2N=200000 -> nb=196)
__global__ __launch_bounds__(256) void scan2_kernel(
    int* __restrict__ bsums, int nb, int* __restrict__ offsets, int n)
{
    __shared__ int b[2][256];
    const int tid = threadIdx.x;
    int val = (tid < nb) ? bsums[tid] : 0;
    int cur = 0;
    b[0][tid] = val;
    __syncthreads();
    for (int off = 1; off < 256; off <<= 1) {
        int x = b[cur][tid];
        if (tid >= off) x += b[cur][tid - off];
        b[cur ^ 1][tid] = x;
        cur ^= 1;
        __syncthreads();
    }
    if (tid < nb) bsums[tid] = b[cur][tid] - val;      // exclusive
    if (tid == 255) offsets[n] = b[cur][255];          // grand total
}

__global__ __launch_bounds__(256) void scan3_kernel(
    int* __restrict__ offsets, const int* __restrict__ bsums, int n)
{
    int idx = blockIdx.x * 256 + threadIdx.x;
    if (idx < n) offsets[idx] += bsums[idx >> 10];
}

__global__ __launch_bounds__(256) void place2_kernel(
    const int* __restrict__ tgt_m, int E,
    const int* __restrict__ tgt_h, int Eh,
    const int* __restrict__ offsets, int* __restrict__ cursors,
    int* __restrict__ perm, int N)
{
    int i = blockIdx.x * 256 + threadIdx.x;
    if (i < E) {
        int slot = tgt_m[i];
        int pos = offsets[slot] + atomicAdd(&cursors[slot], 1);
        perm[pos] = i;                      // main edge id
    } else if (i < E + Eh) {
        int slot = N + tgt_h[i - E];
        int pos = offsets[slot] + atomicAdd(&cursors[slot], 1);
        perm[pos] = i - E;                  // hull-local edge id
    }
}

// ---------------------------------------------------------------------------
// Convert 5 weight matrices fp32 -> bf16 into ws: W1|W1h|W2|W2h|Wc  (98304)
// ---------------------------------------------------------------------------
__global__ __launch_bounds__(256) void wconvert_kernel(
    const float* __restrict__ W1, const float* __restrict__ W1h,
    const float* __restrict__ W2, const float* __restrict__ W2h,
    const float* __restrict__ Wc, u16* __restrict__ dst)
{
    int i = blockIdx.x * 256 + threadIdx.x;
    if (i >= 98304) return;
    const float* src; int off;
    if      (i < 16384) { src = W1;  off = i; }
    else if (i < 32768) { src = W1h; off = i - 16384; }
    else if (i < 49152) { src = W2;  off = i - 32768; }
    else if (i < 65536) { src = W2h; off = i - 49152; }
    else                { src = Wc;  off = i - 65536; }
    dst[i] = f2bf(src[off]);
}

// ---------------------------------------------------------------------------
// Fused gather + 3-layer MFMA MLP. Block = 64 nodes x 4 waves, NO barriers:
// each wave owns rows [w*16, w*16+16) of every LDS tile. IN-PLACE layers:
// layer128 loads the wave's whole 16x128 input stripe into af[4] registers
// BEFORE writing, so each layer overwrites its own input tile (wave-local,
// LDS program order guarantees write->read ordering within the wave).
// Only 2 tiles (32KB) -> 5 blocks/CU LDS-limit (vs 3 tiles/12 waves in R6).
//   gather: e->X0, eh->X1
//   L1m: X0->X0   L1h: X1->X1   L2m: X0->X0   L2h: X1->X1
//   final: X0(zm), X1(zh) -> out
// LDS tiles [64][128] bf16 XOR chunk-swizzled: chunk' = c ^ (row&7).
// ---------------------------------------------------------------------------
#define MT 64

#define CHUNK_IDX(row, ch) (((row) * 16 + ((ch) ^ ((row) & 7))))
#define AFRAG(ls, row, ch) (*(const short8*)&(ls)[CHUNK_IDX(row, ch) * 8])

__device__ __forceinline__ f32x4 gather_rows(
    const f32x4* __restrict__ src, const int* __restrict__ perm,
    int k, int kend, int c4)
{
    f32x4 s = {0.f, 0.f, 0.f, 0.f};
    for (; k + 4 <= kend; k += 4) {
        int p0 = perm[k], p1 = perm[k + 1], p2 = perm[k + 2], p3 = perm[k + 3];
        f32x4 a = __builtin_nontemporal_load(&src[(size_t)p0 * 32 + c4]);
        f32x4 b = __builtin_nontemporal_load(&src[(size_t)p1 * 32 + c4]);
        f32x4 c = __builtin_nontemporal_load(&src[(size_t)p2 * 32 + c4]);
        f32x4 d = __builtin_nontemporal_load(&src[(size_t)p3 * 32 + c4]);
        s += (a + b) + (c + d);
    }
    for (; k + 2 <= kend; k += 2) {
        int p0 = perm[k], p1 = perm[k + 1];
        s += __builtin_nontemporal_load(&src[(size_t)p0 * 32 + c4])
           + __builtin_nontemporal_load(&src[(size_t)p1 * 32 + c4]);
    }
    if (k < kend)
        s += __builtin_nontemporal_load(&src[(size_t)perm[k] * 32 + c4]);
    return s;
}

// In-place layer: ls is both input and output tile (wave-local stripe).
__device__ __forceinline__ void layer128(
    u16* __restrict__ ls, const u16* __restrict__ W,
    const float* __restrict__ bias,
    int rw, int lr, int kc, bool act)
{
    const int arow = rw + lr;
    short8 af[4];
    #pragma unroll
    for (int s = 0; s < 4; s++) af[s] = AFRAG(ls, arow, s * 4 + kc);
    #pragma unroll
    for (int nt = 0; nt < 8; nt++) {
        const int bcol = nt * 16 + lr;
        const short8* wr = (const short8*)(W + bcol * 128);
        f32x4 acc = {0.f, 0.f, 0.f, 0.f};
        #pragma unroll
        for (int s = 0; s < 4; s++)
            acc = __builtin_amdgcn_mfma_f32_16x16x32_bf16(af[s], wr[s * 4 + kc], acc, 0, 0, 0);
        const float bn = bias[bcol];
        #pragma unroll
        for (int r = 0; r < 4; r++) {
            const int drow = rw + kc * 4 + r;
            float val = acc[r] + bn;
            if (act) val = ssp(val);
            ls[CHUNK_IDX(drow, bcol >> 3) * 8 + (bcol & 7)] = f2bf(val);
        }
    }
}

__global__ __launch_bounds__(256) void fused_mlp_kernel(
    const float* __restrict__ e, const float* __restrict__ eh,
    const int* __restrict__ perm, const int* __restrict__ offsets,
    const u16* __restrict__ Wbf,
    const float* __restrict__ b1, const float* __restrict__ b1h,
    const float* __restrict__ b2, const float* __restrict__ b2h,
    const float* __restrict__ bc,
    const float* __restrict__ v, float* __restrict__ out, int n)
{
    __shared__ __align__(16) u16 X0[MT * 128];
    __shared__ __align__(16) u16 X1[MT * 128];

    const int tid = threadIdx.x;
    const int l   = tid & 63;
    const int w   = tid >> 6;
    const int rw  = w * 16;
    const int lr  = l & 15;
    const int kc  = l >> 4;
    const int node0 = blockIdx.x * MT;

    const u16* W1  = Wbf;
    const u16* W1h = Wbf + 16384;
    const u16* W2  = Wbf + 32768;
    const u16* W2h = Wbf + 49152;
    const u16* Wc  = Wbf + 65536;

    // ---- per-wave gather: 2 nodes at a time (one per 32-lane half) ----
    const int hw = l >> 5;
    const int c4 = l & 31;
    const int ch = c4 >> 1;
    const int hf = (c4 & 1) * 4;
    for (int j = hw; j < 16; j += 2) {
        const int row  = rw + j;
        const int node = node0 + row;
        f32x4 sm = {0.f, 0.f, 0.f, 0.f};
        f32x4 sh = {0.f, 0.f, 0.f, 0.f};
        if (node < n) {
            sm = gather_rows((const f32x4*)e,  perm, offsets[node],     offsets[node + 1],     c4);
            sh = gather_rows((const f32x4*)eh, perm, offsets[n + node], offsets[n + node + 1], c4);
        }
        ushort4 om, oh;
        om.x = f2bf(sm.x); om.y = f2bf(sm.y); om.z = f2bf(sm.z); om.w = f2bf(sm.w);
        oh.x = f2bf(sh.x); oh.y = f2bf(sh.y); oh.z = f2bf(sh.z); oh.w = f2bf(sh.w);
        *(ushort4*)&X0[CHUNK_IDX(row, ch) * 8 + hf] = om;
        *(ushort4*)&X1[CHUNK_IDX(row, ch) * 8 + hf] = oh;
    }

    // ---- 3-layer MFMA chain, wave-local, in-place (no barriers) ----
    layer128(X0, W1,  b1,  rw, lr, kc, true);    // h1m
    layer128(X1, W1h, b1h, rw, lr, kc, true);    // h1h
    layer128(X0, W2,  b2,  rw, lr, kc, false);   // zm
    layer128(X1, W2h, b2h, rw, lr, kc, false);   // zh

    // ---- final: out = v + ssp(cat(zm,zh) @ Wc^T + bc) ----
    {
        const int arow = rw + lr;
        short8 af[8];
        #pragma unroll
        for (int s = 0; s < 4; s++) af[s]     = AFRAG(X0, arow, s * 4 + kc);
        #pragma unroll
        for (int s = 0; s < 4; s++) af[s + 4] = AFRAG(X1, arow, s * 4 + kc);
        #pragma unroll
        for (int nt = 0; nt < 8; nt++) {
            const int bcol = nt * 16 + lr;
            const short8* wr = (const short8*)(Wc + bcol * 256);
            f32x4 acc = {0.f, 0.f, 0.f, 0.f};
            #pragma unroll
            for (int s = 0; s < 8; s++)
                acc = __builtin_amdgcn_mfma_f32_16x16x32_bf16(af[s], wr[s * 4 + kc], acc, 0, 0, 0);
            const float bn = bc[bcol];
            #pragma unroll
            for (int r = 0; r < 4; r++) {
                const int drow = rw + kc * 4 + r;
                const int node = node0 + drow;
                if (node < n) {
                    size_t off = (size_t)node * 128 + bcol;
                    out[off] = v[off] + ssp(acc[r] + bn);
                }
            }
        }
    }
}

extern "C" void kernel_launch(void* const* d_in, const int* in_sizes, int n_in,
                              void* d_out, int out_size, void* d_ws, size_t ws_size,
                              hipStream_t stream)
{
    const float* v    = (const float*)d_in[0];
    const float* e    = (const float*)d_in[1];
    const int*   ei   = (const int*)  d_in[2];
    const float* eh   = (const float*)d_in[3];
    const int*   eih  = (const int*)  d_in[4];
    const float* W1   = (const float*)d_in[5];
    const float* b1   = (const float*)d_in[6];
    const float* W2   = (const float*)d_in[7];
    const float* b2   = (const float*)d_in[8];
    const float* W1h  = (const float*)d_in[9];
    const float* b1h  = (const float*)d_in[10];
    const float* W2h  = (const float*)d_in[11];
    const float* b2h  = (const float*)d_in[12];
    const float* Wc   = (const float*)d_in[13];
    const float* bc   = (const float*)d_in[14];
    float* out = (float*)d_out;

    const int N  = in_sizes[0] / 128;
    const int E  = (int)(in_sizes[1] / 128);
    const int Eh = (int)(in_sizes[3] / 128);
    const int n2 = 2 * N;

    // workspace layout (all 16B-aligned)
    u16* Wbf     = (u16*)d_ws;                   // 98304 bf16
    int* counts  = (int*)(Wbf + 98304);          // 2N
    int* cursors = counts + n2;                  // 2N (contiguous with counts)
    int* offsets = cursors + n2;                 // 2N+1
    int* bsums   = offsets + (n2 + 1);           // 256
    int* perm    = bsums + 256;                  // E + Eh

    const int* tgt_m = ei  + E;   // edge_index row 1 = targets
    const int* tgt_h = eih + Eh;

    const int NB = (n2 + 1023) / 1024;
    const int ET = E + Eh;

    wconvert_kernel<<<(98304 + 255) / 256, 256, 0, stream>>>(W1, W1h, W2, W2h, Wc, Wbf);

    (void)hipMemsetAsync(counts, 0, (size_t)2 * n2 * 4, stream);   // counts + cursors
    hist2_kernel <<<(ET + 255) / 256, 256, 0, stream>>>(tgt_m, E, tgt_h, Eh, counts, N);
    scan1_kernel <<<NB, 1024, 0, stream>>>(counts, offsets, bsums, n2);
    scan2_kernel <<<1, 256, 0, stream>>>(bsums, NB, offsets, n2);
    scan3_kernel <<<(n2 + 255) / 256, 256, 0, stream>>>(offsets, bsums, n2);
    place2_kernel<<<(ET + 255) / 256, 256, 0, stream>>>(tgt_m, E, tgt_h, Eh, offsets, cursors, perm, N);

    fused_mlp_kernel<<<(N + MT - 1) / MT, 256, 0, stream>>>(
        e, eh, perm, offsets, Wbf, b1, b1h, b2, b2h, bc, v, out, N);
}